// Round 11
// baseline (1355.814 us; speedup 1.0000x reference)
//
#include <hip/hip_runtime.h>
#include <math.h>

#define BB 512
#define NN 16
#define CC 256
#define KK 8192
#define BNC (BB*NN*CC)

typedef unsigned short u16;
typedef __attribute__((ext_vector_type(8))) short bf16x8;
typedef __attribute__((ext_vector_type(4))) float f32x4;

__device__ __forceinline__ u16 f2bf(float x) {
    unsigned u = __float_as_uint(x);
    unsigned r = (u + 0x7fffu + ((u >> 16) & 1u)) >> 16;
    return (u16)r;
}

__device__ __forceinline__ void gl2lds16(const void* g, void* l) {
    __builtin_amdgcn_global_load_lds(
        (const __attribute__((address_space(1))) void*)g,
        (__attribute__((address_space(3))) void*)l,
        16, 0, 0);
}

__device__ __forceinline__ void gl2lds4(const void* g, void* l) {
    __builtin_amdgcn_global_load_lds(
        (const __attribute__((address_space(1))) void*)g,
        (__attribute__((address_space(3))) void*)l,
        4, 0, 0);
}

// ---------------------------------------------------------------------------
// stores 0.5*|e|^2 (folded into MFMA acc init in dist kernel)
__global__ void esq_kernel(const float* __restrict__ emb, float* __restrict__ e_sq) {
    int gid  = blockIdx.x * blockDim.x + threadIdx.x;
    int wave = gid >> 6;
    int lane = gid & 63;
    const float4 v = *(const float4*)(emb + (size_t)wave * CC + lane * 4);
    float s = v.x*v.x + v.y*v.y + v.z*v.z + v.w*v.w;
    #pragma unroll
    for (int m = 32; m >= 1; m >>= 1) s += __shfl_xor(s, m, 64);
    if (lane == 0) e_sq[wave] = 0.5f * s;
}

// stores NEGATED emb in bf16 so MFMA accumulates 0.5*esq - dot
__global__ void cvt_emb_kernel(const float* __restrict__ emb, u16* __restrict__ out) {
    int gid = blockIdx.x * blockDim.x + threadIdx.x;
    float4 v = ((const float4*)emb)[gid];
    ushort4 o;
    o.x = f2bf(-v.x); o.y = f2bf(-v.y); o.z = f2bf(-v.z); o.w = f2bf(-v.w);
    ((ushort4*)out)[gid] = o;
}

// initial pool for pn=1
__global__ void init_pool_kernel(const float* __restrict__ f,
                                 u16* __restrict__ rest_bf) {
    int b = blockIdx.x;
    int c = threadIdx.x;
    const float* base = f + (size_t)b * NN * CC + c;
    float acc = 0.f;
    #pragma unroll
    for (int n = 0; n < NN; ++n) acc += base[(size_t)n * CC];
    rest_bf[(size_t)b * CC + c] = f2bf(acc * (1.0f / 16.0f));
}

// ---------------------------------------------------------------------------
__device__ __forceinline__ unsigned long long shfl_xor_u64(unsigned long long v, int m) {
    unsigned lo = (unsigned)v, hi = (unsigned)(v >> 32);
    lo = __shfl_xor(lo, m, 64);
    hi = __shfl_xor(hi, m, 64);
    return ((unsigned long long)hi << 32) | lo;
}

// MFMA distance+argmin, v12 (= v11 + LDS sized for the 3-block regime):
//  v10/v11 post-mortem: the register allocator derives its occupancy
//  target from the LDS-implied blocks/CU, NOT from launch_bounds' min.
//  At 34KB LDS (>=4 blocks feasible) it squeezed VGPRs to 52 and spilled
//  the resident bf fragments (268MB scratch FETCH, 111us). At 66KB
//  (2-block regime, v5-v9) the same code compiles to 88 VGPR, no spill.
//  Fix: size LDS into (40.9KB, 54.6KB] so the LDS-implied max is exactly
//  3 blocks/CU -> allocator budget ~170 regs -> demand ~140 fits, no
//  spill; hardware residency 3 blocks = 12 waves/CU (1.5x v8/v9).
//  - Block = 128 rows (32/wave, bf[2][8]=64 VGPR resident).
//  - Codes double-buffered at HALF-cb granularity (16KB = 4 chunks x 4KB)
//    in the first 32KB of sC; rest of sC is the occupancy-regime pad.
//  - gx granule swizzle via pre-swizzled global source: 0 bank conflicts
//    (proven v6-v11). 1 vmcnt(0)+barrier per half-step.
__global__ __launch_bounds__(256, 2) void dist_mfma_kernel(
        const u16* __restrict__ A, const u16* __restrict__ Bm,
        const float* __restrict__ e_sq,
        unsigned long long* __restrict__ packed, int cpb) {
    __shared__ __align__(16) u16 sC[25600];   // 51.2KB total; ring = first 32KB
    __shared__ __align__(16) float sE[512];   // whole esq strip (cpb <= 512)
    const int tid = threadIdx.x;
    const int w = tid >> 6, l = tid & 63;
    const int r0 = blockIdx.x * 128;
    const int c0 = blockIdx.y * cpb;
    const int NH = cpb >> 5;     // half-steps (4 chunks = 32 dims x 64 codes each)
    const int arow = l & 15;
    const int aq   = l >> 4;

    // ---- resident row fragments: wave owns rows r0+w*32 .. +31 ----
    bf16x8 bf[2][8];
    {
        const u16* fb = A + (((size_t)(r0 + w * 32 + arow)) << 8) + aq * 8;
        #pragma unroll
        for (int j = 0; j < 2; ++j)
            #pragma unroll
            for (int kc = 0; kc < 8; ++kc)
                bf[j][kc] = *(const bf16x8*)(fb + (j << 12) + (kc << 5));
    }

    // ---- esq strip staged whole in prologue (cpb <= 512) ----
    for (int n = tid; n < cpb; n += 256)
        gl2lds4(e_sq + c0 + n, (char*)sE + (size_t)(n - l) * 4);

    // ---- code staging mapping (pre-swizzled source, linear LDS dest) ----
    // thread covers slot s = w*64+l of each 4KB chunk: code crel = s>>2,
    // stored granule (s&3) receives actual granule g = (s&3)^((s>>3)&3).
    const int crel = w * 16 + (l >> 2);
    const int g = (l & 3) ^ ((l >> 3) & 3);
    const u16* Pb = Bm + (((size_t)(c0 + crel)) << 8) + g * 8;

    // stage half-step h_: chunks t = h_*4 .. h_*4+3 (same 64-code group)
    // into half-buffer (h_&1). chunk k-offset within group: (h_&1)*4 + c.
    #define STAGE_H(h_) { \
        const u16* s0_ = Pb + (((size_t)((h_) >> 1)) << 14) + (((h_) & 1) << 7); \
        char* d_ = (char*)sC + (((h_) & 1) << 14) + (w << 10); \
        _Pragma("unroll") \
        for (int c_ = 0; c_ < 4; ++c_) \
            gl2lds16(s0_ + (c_ << 5), d_ + (c_ << 12)); }

    STAGE_H(0)

    const int gx = aq ^ ((arow >> 1) & 3);   // read-side granule swizzle
    float bestd[2];
    int   bestk[2];
    #pragma unroll
    for (int j = 0; j < 2; ++j) { bestd[j] = 1e30f; bestk[j] = 0; }

    asm volatile("s_waitcnt vmcnt(0)" ::: "memory");
    __builtin_amdgcn_s_barrier();
    asm volatile("" ::: "memory");

    f32x4 acc[4][2];
    for (int s = 0; s < NH; ++s) {
        // issue next half's stages first (max flight before the drain)
        if (s + 1 < NH) STAGE_H(s + 1)

        const int cb = s >> 1;
        if (!(s & 1)) {
            #pragma unroll
            for (int i = 0; i < 4; ++i) {
                f32x4 ev = *(const f32x4*)(sE + cb * 64 + i * 16 + (aq << 2));
                #pragma unroll
                for (int j = 0; j < 2; ++j) acc[i][j] = ev;
            }
        }

        const u16* bufp = sC + ((s & 1) << 13);   // u16 units: 16KB half
        #pragma unroll
        for (int c = 0; c < 4; ++c) {
            const int kc = ((s & 1) << 2) + c;    // k-chunk index 0..7
            bf16x8 cf[4];
            const u16* cbp = bufp + (c << 11);
            #pragma unroll
            for (int i = 0; i < 4; ++i)
                cf[i] = *(const bf16x8*)(cbp + ((i * 16 + arow) << 5) + (gx << 3));
            #pragma unroll
            for (int i = 0; i < 4; ++i)
                #pragma unroll
                for (int j = 0; j < 2; ++j)
                    acc[i][j] = __builtin_amdgcn_mfma_f32_16x16x32_bf16(
                                    cf[i], bf[j][kc], acc[i][j], 0, 0, 0);
        }

        if (s & 1) {
            // fold: acc holds 0.5*d for this 64-code group
            #pragma unroll
            for (int i = 0; i < 4; ++i)
                #pragma unroll
                for (int r = 0; r < 4; ++r) {
                    const int k = c0 + cb * 64 + i * 16 + (aq << 2) + r;
                    #pragma unroll
                    for (int j = 0; j < 2; ++j) {
                        const float d = acc[i][j][r];
                        if (d < bestd[j]) { bestd[j] = d; bestk[j] = k; }
                    }
                }
        }

        // own next-half stages landed; own reads of this half retired
        asm volatile("s_waitcnt vmcnt(0) lgkmcnt(0)" ::: "memory");
        __builtin_amdgcn_s_barrier();
        asm volatile("" ::: "memory");
    }
    #undef STAGE_H

    // merge across the 4 aq-lanes holding the same f-row, then global merge
    #pragma unroll
    for (int j = 0; j < 2; ++j) {
        unsigned u = __float_as_uint(bestd[j]);
        u = (u & 0x80000000u) ? ~u : (u | 0x80000000u);
        unsigned long long p = ((unsigned long long)u << 32) | (unsigned)bestk[j];
        unsigned long long o = shfl_xor_u64(p, 16);
        if (o < p) p = o;
        o = shfl_xor_u64(p, 32);
        if (o < p) p = o;
        if (aq == 0)
            atomicMin(&packed[r0 + w * 32 + j * 16 + arow], p);
    }
}

// ---------------------------------------------------------------------------
// Fused: gather + upsample + f_hat/f_rest update + qlat partial + pool for pn+1.
__global__ void update_pool_kernel(const float* __restrict__ f,
                                   const float* __restrict__ emb,
                                   const unsigned long long* __restrict__ packed,
                                   float* __restrict__ f_rest,
                                   float* __restrict__ f_hat,
                                   float* __restrict__ slots,
                                   u16* __restrict__ rest_bf, int pn) {
    int b = blockIdx.x;
    int c = threadIdx.x;
    __shared__ int sk[NN];
    __shared__ float red[4];
    if (threadIdx.x < pn)
        sk[threadIdx.x] = (int)(unsigned)(packed[b * pn + threadIdx.x] & 0xffffffffull);
    __syncthreads();

    float fr[NN];
    float acc_sq = 0.f;
    #pragma unroll
    for (int n = 0; n < NN; ++n) {
        double pos = (n + 0.5) * ((double)pn / 16.0) - 0.5;
        if (pos < 0.0) pos = 0.0;
        int i0 = (int)floor(pos);
        if (i0 > pn - 1) i0 = pn - 1;
        int i1 = i0 + 1;
        if (i1 > pn - 1) i1 = pn - 1;
        double frac = pos - (double)i0;
        float w1 = (float)frac;
        float w0 = (float)(1.0 - frac);
        float h = w0 * emb[(size_t)sk[i0] * CC + c] + w1 * emb[(size_t)sk[i1] * CC + c];
        size_t off = ((size_t)b * NN + n) * CC + c;
        float fh = f_hat[off] + h;
        f_hat[off] = fh;
        float fre = f_rest[off] - h;
        f_rest[off] = fre;
        fr[n] = fre;
        float diff = fh - f[off];
        acc_sq += diff * diff;
    }

    int wv = threadIdx.x >> 6, ln = threadIdx.x & 63;
    #pragma unroll
    for (int m = 32; m >= 1; m >>= 1) acc_sq += __shfl_xor(acc_sq, m, 64);
    if (ln == 0) red[wv] = acc_sq;

    int pn2 = pn + 1;
    if (pn < NN) {
        for (int p = 0; p < pn2; ++p) {
            int s = (p * NN) / pn2;
            int e = ((p + 1) * NN + pn2 - 1) / pn2;
            float v = 0.f;
            for (int n = s; n < e; ++n) v += fr[n];
            v *= 1.0f / (float)(e - s);
            rest_bf[((size_t)(b * pn2 + p)) * CC + c] = f2bf(v);
        }
    }
    __syncthreads();
    if (threadIdx.x == 0)
        atomicAdd(&slots[b & 255], (red[0] + red[1]) + (red[2] + red[3]));
}

// ---------------------------------------------------------------------------
__global__ void final_kernel(const float* __restrict__ slots, float* __restrict__ out_scalars) {
    float v = slots[threadIdx.x];
    #pragma unroll
    for (int m = 32; m >= 1; m >>= 1) v += __shfl_xor(v, m, 64);
    __shared__ float red[4];
    int wv = threadIdx.x >> 6, ln = threadIdx.x & 63;
    if (ln == 0) red[wv] = v;
    __syncthreads();
    if (threadIdx.x == 0) {
        float S = (red[0] + red[1]) + (red[2] + red[3]);
        float qlat = S / (float)BNC / (float)NN;
        out_scalars[0] = 0.25f * qlat;   // commit
        out_scalars[1] = qlat;           // qlat
    }
}

// ---------------------------------------------------------------------------
extern "C" void kernel_launch(void* const* d_in, const int* in_sizes, int n_in,
                              void* d_out, int out_size, void* d_ws, size_t ws_size,
                              hipStream_t stream) {
    (void)in_sizes; (void)n_in; (void)out_size; (void)ws_size;
    const float* f   = (const float*)d_in[0];   // [B, N, C]
    const float* emb = (const float*)d_in[1];   // [K, C]
    float* out = (float*)d_out;                 // f_hat [B*N*C] + 2 scalars

    float* ws      = (float*)d_ws;
    float* f_rest  = ws;                                   // BNC floats
    float* r2_pad  = f_rest + BNC;                         // 8192 (unused, layout keep)
    float* e_sq    = r2_pad + BB * NN;                     // K (0.5*|e|^2)
    float* slots   = e_sq + KK;                            // 256
    unsigned long long* packed_all = (unsigned long long*)(slots + 256);  // 512*136
    u16* rest_bf = (u16*)(packed_all + (size_t)BB * 136);  // 8192*256 bf16
    u16* emb_bf  = rest_bf + (size_t)BB * NN * CC;         // K*C bf16 (negated)

    float* f_hat = out;  // accumulate output in place

    hipMemsetAsync(out, 0, (size_t)BNC * sizeof(float), stream);
    hipMemcpyAsync(f_rest, f, (size_t)BNC * sizeof(float), hipMemcpyDeviceToDevice, stream);
    hipMemsetAsync(slots, 0, 256 * sizeof(float), stream);
    hipMemsetAsync(packed_all, 0xFF, (size_t)BB * 136 * sizeof(unsigned long long), stream);
    esq_kernel<<<KK / 4, 256, 0, stream>>>(emb, e_sq);
    cvt_emb_kernel<<<KK * CC / 4 / 256, 256, 0, stream>>>(emb, emb_bf);
    init_pool_kernel<<<BB, 256, 0, stream>>>(f, rest_bf);

    // splits: 128-row blocks -> grid = (4*pn) x splits; keep cpb >= 64
    static const int splits_tab[17] =
        {0,128,128,128,64,64,64,64,32,32,32,32,32,32,32,32,16};

    for (int pn = 1; pn <= NN; ++pn) {
        unsigned long long* packed = packed_all + (size_t)BB * (pn * (pn - 1) / 2);
        int splits = splits_tab[pn];
        int cpb = KK / splits;
        dim3 grid(BB * pn / 128, splits);
        dist_mfma_kernel<<<grid, 256, 0, stream>>>(rest_bf, emb_bf, e_sq, packed, cpb);
        update_pool_kernel<<<BB, 256, 0, stream>>>(f, emb, packed, f_rest, f_hat,
                                                   slots, rest_bf, pn);
    }
    final_kernel<<<1, 256, 0, stream>>>(slots, out + BNC);
}

// Round 12
// 715.121 us; speedup vs baseline: 1.8959x; 1.8959x over previous
//
#include <hip/hip_runtime.h>
#include <math.h>

#define BB 512
#define NN 16
#define CC 256
#define KK 8192
#define BNC (BB*NN*CC)

typedef unsigned short u16;
typedef __attribute__((ext_vector_type(8))) short bf16x8;
typedef __attribute__((ext_vector_type(4))) float f32x4;

__device__ __forceinline__ u16 f2bf(float x) {
    unsigned u = __float_as_uint(x);
    unsigned r = (u + 0x7fffu + ((u >> 16) & 1u)) >> 16;
    return (u16)r;
}

__device__ __forceinline__ void gl2lds16(const void* g, void* l) {
    __builtin_amdgcn_global_load_lds(
        (const __attribute__((address_space(1))) void*)g,
        (__attribute__((address_space(3))) void*)l,
        16, 0, 0);
}

__device__ __forceinline__ void gl2lds4(const void* g, void* l) {
    __builtin_amdgcn_global_load_lds(
        (const __attribute__((address_space(1))) void*)g,
        (__attribute__((address_space(3))) void*)l,
        4, 0, 0);
}

// ---------------------------------------------------------------------------
// merged: stores negated-bf16 emb AND 0.5*|e|^2 from one pass over emb.
__global__ void esq_cvt_kernel(const float* __restrict__ emb,
                               float* __restrict__ e_sq,
                               u16* __restrict__ out) {
    int gid = blockIdx.x * blockDim.x + threadIdx.x;
    int lane = gid & 63;
    float4 v = ((const float4*)emb)[gid];
    ushort4 o;
    o.x = f2bf(-v.x); o.y = f2bf(-v.y); o.z = f2bf(-v.z); o.w = f2bf(-v.w);
    ((ushort4*)out)[gid] = o;
    float s = v.x*v.x + v.y*v.y + v.z*v.z + v.w*v.w;
    #pragma unroll
    for (int m = 32; m >= 1; m >>= 1) s += __shfl_xor(s, m, 64);
    if (lane == 0) e_sq[gid >> 6] = 0.5f * s;
}

// initial pool for pn=1
__global__ void init_pool_kernel(const float* __restrict__ f,
                                 u16* __restrict__ rest_bf) {
    int b = blockIdx.x;
    int c = threadIdx.x;
    const float* base = f + (size_t)b * NN * CC + c;
    float acc = 0.f;
    #pragma unroll
    for (int n = 0; n < NN; ++n) acc += base[(size_t)n * CC];
    rest_bf[(size_t)b * CC + c] = f2bf(acc * (1.0f / 16.0f));
}

// ---------------------------------------------------------------------------
__device__ __forceinline__ unsigned long long shfl_xor_u64(unsigned long long v, int m) {
    unsigned lo = (unsigned)v, hi = (unsigned)(v >> 32);
    lo = __shfl_xor(lo, m, 64);
    hi = __shfl_xor(hi, m, 64);
    return ((unsigned long long)hi << 32) | lo;
}

// MFMA distance+argmin, v13 (= v8 exact: the best measured structure).
//  Plateau summary (v5-v12): at this tile geometry, 43-50us @pn=16 across
//  four sync structures; occupancy >2 blocks/CU is unreachable because the
//  register allocator couples its VGPR budget to the LDS-implied occupancy
//  (>=66KB LDS -> 88-128 VGPR no spill; <=53KB -> squeeze to 52-68 + 125MB
//  scratch spill, regardless of launch_bounds). So: 66KB LDS, 2 blocks/CU,
//  cb-level double buffer, 1 vmcnt(0)+barrier per 128 MFMAs (v8 = 43.2us).
__global__ __launch_bounds__(256, 2) void dist_mfma_kernel(
        const u16* __restrict__ A, const u16* __restrict__ Bm,
        const float* __restrict__ e_sq,
        unsigned long long* __restrict__ packed, int cpb) {
    __shared__ __align__(16) u16 sC[32768];   // 64KB: 2 cb-buffers x 32KB
    __shared__ __align__(16) float sE[512];   // whole esq strip for this block
    const int tid = threadIdx.x;
    const int w = tid >> 6, l = tid & 63;
    const int r0 = blockIdx.x * 256;
    const int c0 = blockIdx.y * cpb;
    const int ncb2 = cpb >> 6;   // 64-code cb-groups
    const int arow = l & 15;
    const int aq   = l >> 4;

    // ---- resident row fragments ----
    bf16x8 bf[4][8];
    {
        const u16* fb = A + (((size_t)(r0 + w * 64 + arow)) << 8) + aq * 8;
        #pragma unroll
        for (int j = 0; j < 4; ++j)
            #pragma unroll
            for (int kc = 0; kc < 8; ++kc)
                bf[j][kc] = *(const bf16x8*)(fb + (j << 12) + (kc << 5));
    }

    // ---- esq strip staged whole in prologue (cpb <= 512) ----
    for (int n = tid; n < cpb; n += 256)
        gl2lds4(e_sq + c0 + n, (char*)sE + (size_t)(n - l) * 4);

    // ---- code staging mapping (pre-swizzled source, linear LDS dest) ----
    const int crel = w * 16 + (l >> 2);
    const int g = (l & 3) ^ ((l >> 3) & 3);
    const u16* Pb = Bm + (((size_t)(c0 + crel)) << 8) + g * 8;

    // stage all 8 chunks of cb-group cb_ into buffer (cb_&1)
    #define STAGE_CB(cb_) { \
        const u16* s0_ = Pb + ((size_t)(cb_) << 14); \
        char* d0_ = (char*)sC + (((cb_) & 1) << 15) + (w << 10); \
        _Pragma("unroll") \
        for (int c_ = 0; c_ < 8; ++c_) \
            gl2lds16(s0_ + (c_ << 5), d0_ + (c_ << 12)); }

    STAGE_CB(0)

    const int gx = aq ^ ((arow >> 1) & 3);   // read-side granule swizzle
    float bestd[4];
    int   bestk[4];
    #pragma unroll
    for (int j = 0; j < 4; ++j) { bestd[j] = 1e30f; bestk[j] = 0; }

    asm volatile("s_waitcnt vmcnt(0)" ::: "memory");
    __builtin_amdgcn_s_barrier();
    asm volatile("" ::: "memory");

    for (int cb = 0; cb < ncb2; ++cb) {
        // burst-issue next cb's stages (max flight time before the drain)
        if (cb + 1 < ncb2) STAGE_CB(cb + 1)

        f32x4 acc[4][4];
        #pragma unroll
        for (int i = 0; i < 4; ++i) {
            f32x4 ev = *(const f32x4*)(sE + cb * 64 + i * 16 + (aq << 2));
            #pragma unroll
            for (int j = 0; j < 4; ++j) acc[i][j] = ev;
        }

        const u16* bufp = sC + ((cb & 1) << 14);   // u16 units: 32KB buffer
        #pragma unroll
        for (int c = 0; c < 8; ++c) {
            bf16x8 cf[4];
            const u16* cbp = bufp + (c << 11);
            #pragma unroll
            for (int i = 0; i < 4; ++i)
                cf[i] = *(const bf16x8*)(cbp + ((i * 16 + arow) << 5) + (gx << 3));
            __builtin_amdgcn_s_setprio(1);
            #pragma unroll
            for (int i = 0; i < 4; ++i)
                #pragma unroll
                for (int j = 0; j < 4; ++j)
                    acc[i][j] = __builtin_amdgcn_mfma_f32_16x16x32_bf16(
                                    cf[i], bf[j][c], acc[i][j], 0, 0, 0);
            __builtin_amdgcn_s_setprio(0);
        }

        // fold (register-only; overlaps tail of in-flight stages)
        #pragma unroll
        for (int i = 0; i < 4; ++i)
            #pragma unroll
            for (int r = 0; r < 4; ++r) {
                const int k = c0 + cb * 64 + i * 16 + (aq << 2) + r;
                #pragma unroll
                for (int j = 0; j < 4; ++j) {
                    const float d = acc[i][j][r];
                    if (d < bestd[j]) { bestd[j] = d; bestk[j] = k; }
                }
            }

        // own stages for cb+1 complete; reads of this buffer retired
        asm volatile("s_waitcnt vmcnt(0) lgkmcnt(0)" ::: "memory");
        __builtin_amdgcn_s_barrier();
        asm volatile("" ::: "memory");
    }
    #undef STAGE_CB

    // merge across the 4 aq-lanes holding the same f-row, then global merge
    #pragma unroll
    for (int j = 0; j < 4; ++j) {
        unsigned u = __float_as_uint(bestd[j]);
        u = (u & 0x80000000u) ? ~u : (u | 0x80000000u);
        unsigned long long p = ((unsigned long long)u << 32) | (unsigned)bestk[j];
        unsigned long long o = shfl_xor_u64(p, 16);
        if (o < p) p = o;
        o = shfl_xor_u64(p, 32);
        if (o < p) p = o;
        if (aq == 0)
            atomicMin(&packed[r0 + w * 64 + j * 16 + arow], p);
    }
}

// ---------------------------------------------------------------------------
// Fused update, v13: f_hat eliminated via the identity f_hat == f - f_rest.
//  - qlat/commit partials: (f_hat - f)^2 = f_rest^2 (after the update).
//  - pn < NN:  update f_rest, pool for pn+1. f and f_hat never touched.
//  - pn == NN: skip the f_rest write (dead after this); write the output
//    f_hat = f - f_rest instead.  Traffic/launch: ~48MB -> ~20-24MB.
__global__ void update_pool_kernel(const float* __restrict__ f,
                                   const float* __restrict__ emb,
                                   const unsigned long long* __restrict__ packed,
                                   float* __restrict__ f_rest,
                                   float* __restrict__ out,
                                   float* __restrict__ slots,
                                   u16* __restrict__ rest_bf, int pn) {
    int b = blockIdx.x;
    int c = threadIdx.x;
    __shared__ int sk[NN];
    __shared__ float red[4];
    if (threadIdx.x < pn)
        sk[threadIdx.x] = (int)(unsigned)(packed[b * pn + threadIdx.x] & 0xffffffffull);
    __syncthreads();

    float fr[NN];
    float acc_sq = 0.f;
    #pragma unroll
    for (int n = 0; n < NN; ++n) {
        double pos = (n + 0.5) * ((double)pn / 16.0) - 0.5;
        if (pos < 0.0) pos = 0.0;
        int i0 = (int)floor(pos);
        if (i0 > pn - 1) i0 = pn - 1;
        int i1 = i0 + 1;
        if (i1 > pn - 1) i1 = pn - 1;
        double frac = pos - (double)i0;
        float w1 = (float)frac;
        float w0 = (float)(1.0 - frac);
        float h = w0 * emb[(size_t)sk[i0] * CC + c] + w1 * emb[(size_t)sk[i1] * CC + c];
        size_t off = ((size_t)b * NN + n) * CC + c;
        float fre = f_rest[off] - h;
        fr[n] = fre;
        acc_sq += fre * fre;
        if (pn < NN) {
            f_rest[off] = fre;
        } else {
            out[off] = f[off] - fre;   // f_hat = f - f_rest
        }
    }

    int wv = threadIdx.x >> 6, ln = threadIdx.x & 63;
    #pragma unroll
    for (int m = 32; m >= 1; m >>= 1) acc_sq += __shfl_xor(acc_sq, m, 64);
    if (ln == 0) red[wv] = acc_sq;

    int pn2 = pn + 1;
    if (pn < NN) {
        for (int p = 0; p < pn2; ++p) {
            int s = (p * NN) / pn2;
            int e = ((p + 1) * NN + pn2 - 1) / pn2;
            float v = 0.f;
            for (int n = s; n < e; ++n) v += fr[n];
            v *= 1.0f / (float)(e - s);
            rest_bf[((size_t)(b * pn2 + p)) * CC + c] = f2bf(v);
        }
    }
    __syncthreads();
    if (threadIdx.x == 0)
        atomicAdd(&slots[b & 255], (red[0] + red[1]) + (red[2] + red[3]));
}

// ---------------------------------------------------------------------------
__global__ void final_kernel(const float* __restrict__ slots, float* __restrict__ out_scalars) {
    float v = slots[threadIdx.x];
    #pragma unroll
    for (int m = 32; m >= 1; m >>= 1) v += __shfl_xor(v, m, 64);
    __shared__ float red[4];
    int wv = threadIdx.x >> 6, ln = threadIdx.x & 63;
    if (ln == 0) red[wv] = v;
    __syncthreads();
    if (threadIdx.x == 0) {
        float S = (red[0] + red[1]) + (red[2] + red[3]);
        float qlat = S / (float)BNC / (float)NN;
        out_scalars[0] = 0.25f * qlat;   // commit
        out_scalars[1] = qlat;           // qlat
    }
}

// ---------------------------------------------------------------------------
extern "C" void kernel_launch(void* const* d_in, const int* in_sizes, int n_in,
                              void* d_out, int out_size, void* d_ws, size_t ws_size,
                              hipStream_t stream) {
    (void)in_sizes; (void)n_in; (void)out_size; (void)ws_size;
    const float* f   = (const float*)d_in[0];   // [B, N, C]
    const float* emb = (const float*)d_in[1];   // [K, C]
    float* out = (float*)d_out;                 // f_hat [B*N*C] + 2 scalars

    float* ws      = (float*)d_ws;
    float* f_rest  = ws;                                   // BNC floats
    float* r2_pad  = f_rest + BNC;                         // 8192 (unused, layout keep)
    float* e_sq    = r2_pad + BB * NN;                     // K (0.5*|e|^2)
    float* slots   = e_sq + KK;                            // 256
    unsigned long long* packed_all = (unsigned long long*)(slots + 256);  // 512*136
    u16* rest_bf = (u16*)(packed_all + (size_t)BB * 136);  // 8192*256 bf16
    u16* emb_bf  = rest_bf + (size_t)BB * NN * CC;         // K*C bf16 (negated)

    hipMemcpyAsync(f_rest, f, (size_t)BNC * sizeof(float), hipMemcpyDeviceToDevice, stream);
    hipMemsetAsync(slots, 0, 256 * sizeof(float), stream);
    hipMemsetAsync(packed_all, 0xFF, (size_t)BB * 136 * sizeof(unsigned long long), stream);
    esq_cvt_kernel<<<KK * CC / 4 / 256, 256, 0, stream>>>(emb, e_sq, emb_bf);
    init_pool_kernel<<<BB, 256, 0, stream>>>(f, rest_bf);

    // splits: target >= 512 blocks where cpb >= 64 allows; cpb = 8192/splits
    static const int splits_tab[17] =
        {0,128,128,128,64,64,64,64,32,32,32,32,32,32,32,32,16};

    for (int pn = 1; pn <= NN; ++pn) {
        unsigned long long* packed = packed_all + (size_t)BB * (pn * (pn - 1) / 2);
        int splits = splits_tab[pn];
        int cpb = KK / splits;
        dim3 grid(BB * pn / 256, splits);
        dist_mfma_kernel<<<grid, 256, 0, stream>>>(rest_bf, emb_bf, e_sq, packed, cpb);
        update_pool_kernel<<<BB, 256, 0, stream>>>(f, emb, packed, f_rest, out,
                                                   slots, rest_bf, pn);
    }
    final_kernel<<<1, 256, 0, stream>>>(slots, out + BNC);
}

// Round 13
// 662.702 us; speedup vs baseline: 2.0459x; 1.0791x over previous
//
#include <hip/hip_runtime.h>
#include <math.h>

#define BB 512
#define NN 16
#define CC 256
#define KK 8192
#define BNC (BB*NN*CC)

typedef unsigned short u16;
typedef __attribute__((ext_vector_type(8))) short bf16x8;
typedef __attribute__((ext_vector_type(4))) float f32x4;

__device__ __forceinline__ u16 f2bf(float x) {
    unsigned u = __float_as_uint(x);
    unsigned r = (u + 0x7fffu + ((u >> 16) & 1u)) >> 16;
    return (u16)r;
}

__device__ __forceinline__ void gl2lds16(const void* g, void* l) {
    __builtin_amdgcn_global_load_lds(
        (const __attribute__((address_space(1))) void*)g,
        (__attribute__((address_space(3))) void*)l,
        16, 0, 0);
}

__device__ __forceinline__ void gl2lds4(const void* g, void* l) {
    __builtin_amdgcn_global_load_lds(
        (const __attribute__((address_space(1))) void*)g,
        (__attribute__((address_space(3))) void*)l,
        4, 0, 0);
}

// ---------------------------------------------------------------------------
// merged: stores negated-bf16 emb AND 0.5*|e|^2 from one pass over emb.
__global__ void esq_cvt_kernel(const float* __restrict__ emb,
                               float* __restrict__ e_sq,
                               u16* __restrict__ out) {
    int gid = blockIdx.x * blockDim.x + threadIdx.x;
    int lane = gid & 63;
    float4 v = ((const float4*)emb)[gid];
    ushort4 o;
    o.x = f2bf(-v.x); o.y = f2bf(-v.y); o.z = f2bf(-v.z); o.w = f2bf(-v.w);
    ((ushort4*)out)[gid] = o;
    float s = v.x*v.x + v.y*v.y + v.z*v.z + v.w*v.w;
    #pragma unroll
    for (int m = 32; m >= 1; m >>= 1) s += __shfl_xor(s, m, 64);
    if (lane == 0) e_sq[gid >> 6] = 0.5f * s;
}

// initial pool for pn=1
__global__ void init_pool_kernel(const float* __restrict__ f,
                                 u16* __restrict__ rest_bf) {
    int b = blockIdx.x;
    int c = threadIdx.x;
    const float* base = f + (size_t)b * NN * CC + c;
    float acc = 0.f;
    #pragma unroll
    for (int n = 0; n < NN; ++n) acc += base[(size_t)n * CC];
    rest_bf[(size_t)b * CC + c] = f2bf(acc * (1.0f / 16.0f));
}

// ---------------------------------------------------------------------------
__device__ __forceinline__ unsigned long long shfl_xor_u64(unsigned long long v, int m) {
    unsigned lo = (unsigned)v, hi = (unsigned)(v >> 32);
    lo = __shfl_xor(lo, m, 64);
    hi = __shfl_xor(hi, m, 64);
    return ((unsigned long long)hi << 32) | lo;
}

// MFMA distance+argmin, v14 (4 waves/SIMD in the proven 66KB-LDS regime):
//  v13 floor arithmetic (per-SIMD matrix pipe): pn=16 MFMA floor ~16.6us,
//  ds_read ~10, VALU ~9 -- measured 48 with all pipes ~25-35% busy =
//  latency un-hidden at 2 waves/SIMD. The proven no-spill regime is
//  66KB LDS (v5-v9: >=66KB -> ~88-116 VGPR clean; <=53KB -> squeeze+spill
//  regardless of bounds). To double TLP WITHOUT leaving it: 512-thread
//  blocks (8 waves x 32 rows = same 256 rows/block, same grid), same
//  66KB LDS. v9 proved the 32-row/wave structure = 88 VGPR + 32 acc
//  AGPR = 120 total -> hardware hosts 4 waves/SIMD (16 waves/CU).
//  launch_bounds(512,2) keeps the allocator's budget permissive (256);
//  residency follows the actual ~120 regs.
//  - Codes: block-shared cb-level double buffer (2 x 32KB); wave w stages
//    chunk w (4 x 1KB gl2lds16, dest linear in lane: byte = 16*l).
//  - Granule swizzle unchanged: stored (l&3) <- actual (l&3)^((l>>3)&3);
//    read gx = aq ^ ((arow>>1)&3). (i*16 code shifts don't touch
//    (code>>1)&3.) 0 bank conflicts, proven v6-v13.
//  - 1 vmcnt(0)+barrier per cb (128 MFMAs/wave... 64 here).
__global__ __launch_bounds__(512, 2) void dist_mfma_kernel(
        const u16* __restrict__ A, const u16* __restrict__ Bm,
        const float* __restrict__ e_sq,
        unsigned long long* __restrict__ packed, int cpb) {
    __shared__ __align__(16) u16 sC[32768];   // 64KB: 2 cb-buffers x 32KB
    __shared__ __align__(16) float sE[512];   // whole esq strip for this block
    const int tid = threadIdx.x;
    const int w = tid >> 6, l = tid & 63;     // 8 waves
    const int r0 = blockIdx.x * 256;
    const int c0 = blockIdx.y * cpb;
    const int ncb2 = cpb >> 6;   // 64-code cb-groups
    const int arow = l & 15;
    const int aq   = l >> 4;

    // ---- resident row fragments: wave owns rows r0+w*32 .. +31 ----
    bf16x8 bf[2][8];
    {
        const u16* fb = A + (((size_t)(r0 + w * 32 + arow)) << 8) + aq * 8;
        #pragma unroll
        for (int j = 0; j < 2; ++j)
            #pragma unroll
            for (int kc = 0; kc < 8; ++kc)
                bf[j][kc] = *(const bf16x8*)(fb + (j << 12) + (kc << 5));
    }

    // ---- esq strip staged whole in prologue (cpb <= 512) ----
    for (int n = tid; n < cpb; n += 512)
        gl2lds4(e_sq + c0 + n, (char*)sE + (size_t)(n - l) * 4);

    // ---- code staging: wave w stages chunk w (k-dims [w*32, w*32+32)).
    // issue i covers codes i*16 + (l>>2); stored granule (l&3) receives
    // actual granule g = (l&3)^((l>>3)&3) (pre-swizzled source).
    const int g = (l & 3) ^ ((l >> 3) & 3);
    const u16* Pb = Bm + (((size_t)(c0 + (l >> 2))) << 8) + g * 8;

    #define STAGE_CB(cb_) { \
        const u16* s0_ = Pb + ((size_t)(cb_) << 14) + (w << 5); \
        char* d0_ = (char*)sC + (((cb_) & 1) << 15) + (w << 12); \
        _Pragma("unroll") \
        for (int i_ = 0; i_ < 4; ++i_) \
            gl2lds16(s0_ + (i_ << 12), d0_ + (i_ << 10)); }

    STAGE_CB(0)

    const int gx = aq ^ ((arow >> 1) & 3);   // read-side granule swizzle
    float bestd[2];
    int   bestk[2];
    #pragma unroll
    for (int j = 0; j < 2; ++j) { bestd[j] = 1e30f; bestk[j] = 0; }

    asm volatile("s_waitcnt vmcnt(0)" ::: "memory");
    __builtin_amdgcn_s_barrier();
    asm volatile("" ::: "memory");

    for (int cb = 0; cb < ncb2; ++cb) {
        // burst-issue next cb's stages (max flight time before the drain)
        if (cb + 1 < ncb2) STAGE_CB(cb + 1)

        f32x4 acc[4][2];
        #pragma unroll
        for (int i = 0; i < 4; ++i) {
            f32x4 ev = *(const f32x4*)(sE + cb * 64 + i * 16 + (aq << 2));
            #pragma unroll
            for (int j = 0; j < 2; ++j) acc[i][j] = ev;
        }

        const u16* bufp = sC + ((cb & 1) << 14);   // u16 units: 32KB buffer
        #pragma unroll
        for (int c = 0; c < 8; ++c) {
            bf16x8 cf[4];
            const u16* cbp = bufp + (c << 11);
            #pragma unroll
            for (int i = 0; i < 4; ++i)
                cf[i] = *(const bf16x8*)(cbp + ((i * 16 + arow) << 5) + (gx << 3));
            #pragma unroll
            for (int i = 0; i < 4; ++i)
                #pragma unroll
                for (int j = 0; j < 2; ++j)
                    acc[i][j] = __builtin_amdgcn_mfma_f32_16x16x32_bf16(
                                    cf[i], bf[j][c], acc[i][j], 0, 0, 0);
        }

        // fold (register-only; overlaps tail of in-flight stages)
        #pragma unroll
        for (int i = 0; i < 4; ++i)
            #pragma unroll
            for (int r = 0; r < 4; ++r) {
                const int k = c0 + cb * 64 + i * 16 + (aq << 2) + r;
                #pragma unroll
                for (int j = 0; j < 2; ++j) {
                    const float d = acc[i][j][r];
                    if (d < bestd[j]) { bestd[j] = d; bestk[j] = k; }
                }
            }

        // own stages for cb+1 complete; reads of this buffer retired
        asm volatile("s_waitcnt vmcnt(0) lgkmcnt(0)" ::: "memory");
        __builtin_amdgcn_s_barrier();
        asm volatile("" ::: "memory");
    }
    #undef STAGE_CB

    // merge across the 4 aq-lanes holding the same f-row, then global merge
    #pragma unroll
    for (int j = 0; j < 2; ++j) {
        unsigned u = __float_as_uint(bestd[j]);
        u = (u & 0x80000000u) ? ~u : (u | 0x80000000u);
        unsigned long long p = ((unsigned long long)u << 32) | (unsigned)bestk[j];
        unsigned long long o = shfl_xor_u64(p, 16);
        if (o < p) p = o;
        o = shfl_xor_u64(p, 32);
        if (o < p) p = o;
        if (aq == 0)
            atomicMin(&packed[r0 + w * 32 + j * 16 + arow], p);
    }
}

// ---------------------------------------------------------------------------
// Fused update: f_hat eliminated via f_hat == f - f_rest (v13).
__global__ void update_pool_kernel(const float* __restrict__ f,
                                   const float* __restrict__ emb,
                                   const unsigned long long* __restrict__ packed,
                                   float* __restrict__ f_rest,
                                   float* __restrict__ out,
                                   float* __restrict__ slots,
                                   u16* __restrict__ rest_bf, int pn) {
    int b = blockIdx.x;
    int c = threadIdx.x;
    __shared__ int sk[NN];
    __shared__ float red[4];
    if (threadIdx.x < pn)
        sk[threadIdx.x] = (int)(unsigned)(packed[b * pn + threadIdx.x] & 0xffffffffull);
    __syncthreads();

    float fr[NN];
    float acc_sq = 0.f;
    #pragma unroll
    for (int n = 0; n < NN; ++n) {
        double pos = (n + 0.5) * ((double)pn / 16.0) - 0.5;
        if (pos < 0.0) pos = 0.0;
        int i0 = (int)floor(pos);
        if (i0 > pn - 1) i0 = pn - 1;
        int i1 = i0 + 1;
        if (i1 > pn - 1) i1 = pn - 1;
        double frac = pos - (double)i0;
        float w1 = (float)frac;
        float w0 = (float)(1.0 - frac);
        float h = w0 * emb[(size_t)sk[i0] * CC + c] + w1 * emb[(size_t)sk[i1] * CC + c];
        size_t off = ((size_t)b * NN + n) * CC + c;
        float fre = f_rest[off] - h;
        fr[n] = fre;
        acc_sq += fre * fre;
        if (pn < NN) {
            f_rest[off] = fre;
        } else {
            out[off] = f[off] - fre;   // f_hat = f - f_rest
        }
    }

    int wv = threadIdx.x >> 6, ln = threadIdx.x & 63;
    #pragma unroll
    for (int m = 32; m >= 1; m >>= 1) acc_sq += __shfl_xor(acc_sq, m, 64);
    if (ln == 0) red[wv] = acc_sq;

    int pn2 = pn + 1;
    if (pn < NN) {
        for (int p = 0; p < pn2; ++p) {
            int s = (p * NN) / pn2;
            int e = ((p + 1) * NN + pn2 - 1) / pn2;
            float v = 0.f;
            for (int n = s; n < e; ++n) v += fr[n];
            v *= 1.0f / (float)(e - s);
            rest_bf[((size_t)(b * pn2 + p)) * CC + c] = f2bf(v);
        }
    }
    __syncthreads();
    if (threadIdx.x == 0)
        atomicAdd(&slots[b & 255], (red[0] + red[1]) + (red[2] + red[3]));
}

// ---------------------------------------------------------------------------
__global__ void final_kernel(const float* __restrict__ slots, float* __restrict__ out_scalars) {
    float v = slots[threadIdx.x];
    #pragma unroll
    for (int m = 32; m >= 1; m >>= 1) v += __shfl_xor(v, m, 64);
    __shared__ float red[4];
    int wv = threadIdx.x >> 6, ln = threadIdx.x & 63;
    if (ln == 0) red[wv] = v;
    __syncthreads();
    if (threadIdx.x == 0) {
        float S = (red[0] + red[1]) + (red[2] + red[3]);
        float qlat = S / (float)BNC / (float)NN;
        out_scalars[0] = 0.25f * qlat;   // commit
        out_scalars[1] = qlat;           // qlat
    }
}

// ---------------------------------------------------------------------------
extern "C" void kernel_launch(void* const* d_in, const int* in_sizes, int n_in,
                              void* d_out, int out_size, void* d_ws, size_t ws_size,
                              hipStream_t stream) {
    (void)in_sizes; (void)n_in; (void)out_size; (void)ws_size;
    const float* f   = (const float*)d_in[0];   // [B, N, C]
    const float* emb = (const float*)d_in[1];   // [K, C]
    float* out = (float*)d_out;                 // f_hat [B*N*C] + 2 scalars

    float* ws      = (float*)d_ws;
    float* f_rest  = ws;                                   // BNC floats
    float* r2_pad  = f_rest + BNC;                         // 8192 (unused, layout keep)
    float* e_sq    = r2_pad + BB * NN;                     // K (0.5*|e|^2)
    float* slots   = e_sq + KK;                            // 256
    unsigned long long* packed_all = (unsigned long long*)(slots + 256);  // 512*136
    u16* rest_bf = (u16*)(packed_all + (size_t)BB * 136);  // 8192*256 bf16
    u16* emb_bf  = rest_bf + (size_t)BB * NN * CC;         // K*C bf16 (negated)

    hipMemcpyAsync(f_rest, f, (size_t)BNC * sizeof(float), hipMemcpyDeviceToDevice, stream);
    hipMemsetAsync(slots, 0, 256 * sizeof(float), stream);
    hipMemsetAsync(packed_all, 0xFF, (size_t)BB * 136 * sizeof(unsigned long long), stream);
    esq_cvt_kernel<<<KK * CC / 4 / 256, 256, 0, stream>>>(emb, e_sq, emb_bf);
    init_pool_kernel<<<BB, 256, 0, stream>>>(f, rest_bf);

    // splits: target >= 512 blocks where cpb >= 64 allows; cpb = 8192/splits
    static const int splits_tab[17] =
        {0,128,128,128,64,64,64,64,32,32,32,32,32,32,32,32,16};

    for (int pn = 1; pn <= NN; ++pn) {
        unsigned long long* packed = packed_all + (size_t)BB * (pn * (pn - 1) / 2);
        int splits = splits_tab[pn];
        int cpb = KK / splits;
        dim3 grid(BB * pn / 256, splits);
        dist_mfma_kernel<<<grid, 512, 0, stream>>>(rest_bf, emb_bf, e_sq, packed, cpb);
        update_pool_kernel<<<BB, 256, 0, stream>>>(f, emb, packed, f_rest, out,
                                                   slots, rest_bf, pn);
    }
    final_kernel<<<1, 256, 0, stream>>>(slots, out + BNC);
}